// Round 1
// baseline (161.588 us; speedup 1.0000x reference)
//
#include <hip/hip_runtime.h>
#include <math.h>

#define DM 512
#define NH 8
#define HD 64
#define BB 2
#define TT 2048
#define CHUNK 64
#define NC (TT / CHUNK)   /* 32 */
#define BH (BB * NH)      /* 16 */
#define ROWS (BB * TT)    /* 4096 */
#define EPSV 1e-6f

// ---------------------------------------------------------------------------
// Kernel 1: fused Q/K/V projection.  y = x @ W + b, optional phi (elu+1),
// scattered to (B,H,T,D) layout.  blockIdx.z selects {Q,K,V}.
// 64x64 output tile per block, 256 threads, 4x4 micro-tile, BK=16.
// ---------------------------------------------------------------------------
__global__ __launch_bounds__(256) void proj_kernel(
    const float* __restrict__ x,
    const float* __restrict__ Wq, const float* __restrict__ bq,
    const float* __restrict__ Wk, const float* __restrict__ bk,
    const float* __restrict__ Wv, const float* __restrict__ bv,
    float* __restrict__ q, float* __restrict__ k, float* __restrict__ v)
{
    const int which = blockIdx.z;
    const float* W    = (which == 0) ? Wq : (which == 1) ? Wk : Wv;
    const float* bias = (which == 0) ? bq : (which == 1) ? bk : bv;
    float* dst        = (which == 0) ? q  : (which == 1) ? k  : v;

    __shared__ float As[16][64 + 4];   // As[k][m]  (A tile transposed)
    __shared__ float Bs[16][64 + 4];   // Bs[k][n]

    const int tid = threadIdx.x;
    const int ti = tid >> 4, tj = tid & 15;
    const int r0 = blockIdx.x * 64;
    const int c0 = blockIdx.y * 64;

    const int ar = tid >> 2, ac = (tid & 3) * 4;   // A-tile stage: 64 rows x 16 cols
    const int br = tid >> 4, bc = (tid & 15) * 4;  // B-tile stage: 16 rows x 64 cols

    float acc[4][4] = {};

    for (int k0 = 0; k0 < DM; k0 += 16) {
        float4 a4 = *(const float4*)&x[(size_t)(r0 + ar) * DM + k0 + ac];
        float4 b4 = *(const float4*)&W[(size_t)(k0 + br) * DM + c0 + bc];
        __syncthreads();
        As[ac + 0][ar] = a4.x;
        As[ac + 1][ar] = a4.y;
        As[ac + 2][ar] = a4.z;
        As[ac + 3][ar] = a4.w;
        *(float4*)&Bs[br][bc] = b4;
        __syncthreads();
#pragma unroll
        for (int kk = 0; kk < 16; ++kk) {
            float4 av  = *(const float4*)&As[kk][ti * 4];
            float4 bv4 = *(const float4*)&Bs[kk][tj * 4];
            float am[4] = {av.x, av.y, av.z, av.w};
            float bm[4] = {bv4.x, bv4.y, bv4.z, bv4.w};
#pragma unroll
            for (int i = 0; i < 4; ++i)
#pragma unroll
                for (int j = 0; j < 4; ++j)
                    acc[i][j] = fmaf(am[i], bm[j], acc[i][j]);
        }
    }

    const bool do_phi = (which < 2);
#pragma unroll
    for (int i = 0; i < 4; ++i) {
        const int row = r0 + ti * 4 + i;          // [0, 4096)
        const int b = row >> 11, t = row & (TT - 1);
#pragma unroll
        for (int j = 0; j < 4; ++j) {
            const int col = c0 + tj * 4 + j;      // [0, 512)
            float y = acc[i][j] + bias[col];
            if (do_phi) y = (y > 0.f) ? (y + 1.f) : expf(y);
            const int h = col >> 6, d = col & 63;
            dst[((size_t)(b * NH + h) * TT + t) * HD + d] = y;
        }
    }
}

// ---------------------------------------------------------------------------
// Kernel 2: per-chunk sums.  For each (bh, chunk): KV = sum_t K_t (outer) V_t
// (64x64) and z = sum_t K_t (64).
// ---------------------------------------------------------------------------
__global__ __launch_bounds__(256) void chunk_sums(
    const float* __restrict__ k, const float* __restrict__ v,
    float* __restrict__ kvsum, float* __restrict__ zsum)
{
    const int blk = blockIdx.x;          // bh * NC + c
    const int bh = blk / NC, c = blk % NC;
    const int t0 = c * CHUNK;

    __shared__ float Ks[CHUNK][HD];
    __shared__ float Vs[CHUNK][HD];

    const int tid = threadIdx.x;
    const float* kb = k + ((size_t)bh * TT + t0) * HD;
    const float* vb = v + ((size_t)bh * TT + t0) * HD;

#pragma unroll
    for (int i = 0; i < 4; ++i) {
        const int f = tid + i * 256;             // float4 index, 1024 total
        const int row = f >> 4, col = (f & 15) * 4;
        *(float4*)&Ks[row][col] = *(const float4*)&kb[row * HD + col];
        *(float4*)&Vs[row][col] = *(const float4*)&vb[row * HD + col];
    }
    __syncthreads();

    const int ti = tid >> 4, tj = tid & 15;
    float acc[4][4] = {};
    for (int t = 0; t < CHUNK; ++t) {
        float4 k4 = *(const float4*)&Ks[t][ti * 4];
        float4 v4 = *(const float4*)&Vs[t][tj * 4];
        float km[4] = {k4.x, k4.y, k4.z, k4.w};
        float vm[4] = {v4.x, v4.y, v4.z, v4.w};
#pragma unroll
        for (int i = 0; i < 4; ++i)
#pragma unroll
            for (int j = 0; j < 4; ++j)
                acc[i][j] = fmaf(km[i], vm[j], acc[i][j]);
    }

    float* dst = kvsum + (size_t)blk * (HD * HD);
#pragma unroll
    for (int i = 0; i < 4; ++i)
#pragma unroll
        for (int j = 0; j < 4; ++j)
            dst[(ti * 4 + i) * HD + tj * 4 + j] = acc[i][j];

    if (tid < HD) {
        float s = 0.f;
        for (int t = 0; t < CHUNK; ++t) s += Ks[t][tid];
        zsum[(size_t)blk * HD + tid] = s;
    }
}

// ---------------------------------------------------------------------------
// Kernel 3: exclusive prefix over the NC chunks (in-place: chunk sums ->
// state-before-chunk).  grid = (BH, 17): y<16 handles 256 KV elements each,
// y==16 handles z.
// ---------------------------------------------------------------------------
__global__ __launch_bounds__(256) void prefix_scan(
    float* __restrict__ kvsum, float* __restrict__ zsum)
{
    const int bh = blockIdx.x;
    const int seg = blockIdx.y;
    const int tid = threadIdx.x;

    if (seg < 16) {
        const int e = seg * 256 + tid;           // [0, 4096)
        float run = 0.f;
        for (int c = 0; c < NC; ++c) {
            const size_t idx = (size_t)(bh * NC + c) * (HD * HD) + e;
            const float val = kvsum[idx];
            kvsum[idx] = run;
            run += val;
        }
    } else if (tid < HD) {
        float run = 0.f;
        for (int c = 0; c < NC; ++c) {
            const size_t idx = (size_t)(bh * NC + c) * HD + tid;
            const float val = zsum[idx];
            zsum[idx] = run;
            run += val;
        }
    }
}

// ---------------------------------------------------------------------------
// Kernel 4: per-chunk attention output.
// out = (tril(Q K^T) V + Q S_prev) / max(Q z_prev + rowsum(tril(Q K^T)), eps)
// Written to attn in (B, T, H*D) row-major so the final GEMM reads it plain.
// K tile's LDS is reused for the masked score matrix A.
// ---------------------------------------------------------------------------
__global__ __launch_bounds__(256) void chunk_attn(
    const float* __restrict__ q, const float* __restrict__ k,
    const float* __restrict__ v, const float* __restrict__ sprev,
    const float* __restrict__ zprev_g, float* __restrict__ attn)
{
    const int blk = blockIdx.x;
    const int bh = blk / NC, c = blk % NC;
    const int t0 = c * CHUNK;

    __shared__ float Qs[CHUNK][HD + 1];   // +1 pad: row-indexed scalar reads
    __shared__ float KA[CHUNK][HD + 1];   // K tile, then reused for scores A
    __shared__ float Vs[CHUNK][HD];       // row index uniform across wave
    __shared__ float Ss[HD][HD];
    __shared__ float zprev[HD];
    __shared__ float den[CHUNK];

    const int tid = threadIdx.x;
    const float* qb = q + ((size_t)bh * TT + t0) * HD;
    const float* kb = k + ((size_t)bh * TT + t0) * HD;
    const float* vb = v + ((size_t)bh * TT + t0) * HD;
    const float* sb = sprev + (size_t)blk * (HD * HD);

#pragma unroll
    for (int i = 0; i < 4; ++i) {
        const int f = tid + i * 256;
        const int row = f >> 4, col = (f & 15) * 4;
        float4 q4 = *(const float4*)&qb[row * HD + col];
        float4 k4 = *(const float4*)&kb[row * HD + col];
        // padded rows (stride 65 floats) are not 16B aligned -> scalar stores
        Qs[row][col + 0] = q4.x; Qs[row][col + 1] = q4.y;
        Qs[row][col + 2] = q4.z; Qs[row][col + 3] = q4.w;
        KA[row][col + 0] = k4.x; KA[row][col + 1] = k4.y;
        KA[row][col + 2] = k4.z; KA[row][col + 3] = k4.w;
        *(float4*)&Vs[row][col] = *(const float4*)&vb[row * HD + col];
        *(float4*)&Ss[row][col] = *(const float4*)&sb[row * HD + col];
    }
    if (tid < HD) zprev[tid] = zprev_g[(size_t)blk * HD + tid];
    __syncthreads();

    const int ti = tid >> 4, tj = tid & 15;

    // Phase 1: scores sc[i][j] = Q[4ti+i] . K[4tj+j]
    float sc[4][4] = {};
#pragma unroll 8
    for (int d = 0; d < HD; ++d) {
        float qv[4], kv4[4];
#pragma unroll
        for (int i = 0; i < 4; ++i) qv[i] = Qs[ti * 4 + i][d];
#pragma unroll
        for (int j = 0; j < 4; ++j) kv4[j] = KA[tj * 4 + j][d];
#pragma unroll
        for (int i = 0; i < 4; ++i)
#pragma unroll
            for (int j = 0; j < 4; ++j)
                sc[i][j] = fmaf(qv[i], kv4[j], sc[i][j]);
    }
    __syncthreads();   // all K reads complete before overwrite

    // write masked scores into KA
#pragma unroll
    for (int i = 0; i < 4; ++i)
#pragma unroll
        for (int j = 0; j < 4; ++j) {
            const int row = ti * 4 + i, col = tj * 4 + j;
            KA[row][col] = (col <= row) ? sc[i][j] : 0.f;
        }
    __syncthreads();

    // denominators (one thread per query row)
    if (tid < CHUNK) {
        float dsum = 0.f;
        for (int d = 0; d < HD; ++d) dsum = fmaf(Qs[tid][d], zprev[d], dsum);
        for (int j = 0; j < HD; ++j) dsum += KA[tid][j];
        den[tid] = fmaxf(dsum, EPSV);
    }
    __syncthreads();

    // Phase 2: num = A @ V + Q @ S_prev
    float accn[4][4] = {};
#pragma unroll 4
    for (int jj = 0; jj < CHUNK; ++jj) {
        const float4 v4 = *(const float4*)&Vs[jj][tj * 4];
        float am[4];
#pragma unroll
        for (int i = 0; i < 4; ++i) am[i] = KA[ti * 4 + i][jj];
        const float vm[4] = {v4.x, v4.y, v4.z, v4.w};
#pragma unroll
        for (int i = 0; i < 4; ++i)
#pragma unroll
            for (int j = 0; j < 4; ++j)
                accn[i][j] = fmaf(am[i], vm[j], accn[i][j]);
    }
#pragma unroll 4
    for (int d = 0; d < HD; ++d) {
        const float4 s4 = *(const float4*)&Ss[d][tj * 4];
        float qv[4];
#pragma unroll
        for (int i = 0; i < 4; ++i) qv[i] = Qs[ti * 4 + i][d];
        const float sm[4] = {s4.x, s4.y, s4.z, s4.w};
#pragma unroll
        for (int i = 0; i < 4; ++i)
#pragma unroll
            for (int j = 0; j < 4; ++j)
                accn[i][j] = fmaf(qv[i], sm[j], accn[i][j]);
    }

    const int b = bh >> 3, h = bh & 7;
#pragma unroll
    for (int i = 0; i < 4; ++i) {
        const int trow = t0 + ti * 4 + i;
        const float dv = den[ti * 4 + i];
        float* dst = attn + ((size_t)b * TT + trow) * DM + h * HD + tj * 4;
#pragma unroll
        for (int j = 0; j < 4; ++j) dst[j] = accn[i][j] / dv;
    }
}

// ---------------------------------------------------------------------------
// Kernel 5: output projection.  out = attn @ Wo + bo, plain row-major.
// ---------------------------------------------------------------------------
__global__ __launch_bounds__(256) void outproj_kernel(
    const float* __restrict__ a, const float* __restrict__ W,
    const float* __restrict__ bias, float* __restrict__ out)
{
    __shared__ float As[16][64 + 4];
    __shared__ float Bs[16][64 + 4];

    const int tid = threadIdx.x;
    const int ti = tid >> 4, tj = tid & 15;
    const int r0 = blockIdx.x * 64;
    const int c0 = blockIdx.y * 64;

    const int ar = tid >> 2, ac = (tid & 3) * 4;
    const int br = tid >> 4, bc = (tid & 15) * 4;

    float acc[4][4] = {};

    for (int k0 = 0; k0 < DM; k0 += 16) {
        float4 a4 = *(const float4*)&a[(size_t)(r0 + ar) * DM + k0 + ac];
        float4 b4 = *(const float4*)&W[(size_t)(k0 + br) * DM + c0 + bc];
        __syncthreads();
        As[ac + 0][ar] = a4.x;
        As[ac + 1][ar] = a4.y;
        As[ac + 2][ar] = a4.z;
        As[ac + 3][ar] = a4.w;
        *(float4*)&Bs[br][bc] = b4;
        __syncthreads();
#pragma unroll
        for (int kk = 0; kk < 16; ++kk) {
            float4 av  = *(const float4*)&As[kk][ti * 4];
            float4 bv4 = *(const float4*)&Bs[kk][tj * 4];
            float am[4] = {av.x, av.y, av.z, av.w};
            float bm[4] = {bv4.x, bv4.y, bv4.z, bv4.w};
#pragma unroll
            for (int i = 0; i < 4; ++i)
#pragma unroll
                for (int j = 0; j < 4; ++j)
                    acc[i][j] = fmaf(am[i], bm[j], acc[i][j]);
        }
    }

#pragma unroll
    for (int i = 0; i < 4; ++i) {
        const int row = r0 + ti * 4 + i;
#pragma unroll
        for (int j = 0; j < 4; ++j) {
            const int col = c0 + tj * 4 + j;
            out[(size_t)row * DM + col] = acc[i][j] + bias[col];
        }
    }
}

// ---------------------------------------------------------------------------
extern "C" void kernel_launch(void* const* d_in, const int* in_sizes, int n_in,
                              void* d_out, int out_size, void* d_ws, size_t ws_size,
                              hipStream_t stream)
{
    const float* x  = (const float*)d_in[0];
    const float* Wq = (const float*)d_in[1];
    const float* bq = (const float*)d_in[2];
    const float* Wk = (const float*)d_in[3];
    const float* bk = (const float*)d_in[4];
    const float* Wv = (const float*)d_in[5];
    const float* bv = (const float*)d_in[6];
    const float* Wo = (const float*)d_in[7];
    const float* bo = (const float*)d_in[8];
    float* out = (float*)d_out;

    float* ws = (float*)d_ws;
    const size_t SZ = (size_t)BH * TT * HD;           // 2,097,152 floats
    float* q     = ws;
    float* k     = q + SZ;
    float* v     = k + SZ;
    float* attn  = v + SZ;
    float* kvsum = attn + SZ;                         // BH*NC*HD*HD = 2,097,152
    float* zsum  = kvsum + (size_t)BH * NC * HD * HD; // BH*NC*HD = 32,768
    // total ws: ~42.1 MB

    proj_kernel<<<dim3(ROWS / 64, DM / 64, 3), 256, 0, stream>>>(
        x, Wq, bq, Wk, bk, Wv, bv, q, k, v);
    chunk_sums<<<BH * NC, 256, 0, stream>>>(k, v, kvsum, zsum);
    prefix_scan<<<dim3(BH, 17), 256, 0, stream>>>(kvsum, zsum);
    chunk_attn<<<BH * NC, 256, 0, stream>>>(q, k, v, kvsum, zsum, attn);
    outproj_kernel<<<dim3(ROWS / 64, DM / 64), 256, 0, stream>>>(attn, Wo, bo, out);
}

// Round 2
// 77.426 us; speedup vs baseline: 2.0870x; 2.0870x over previous
//
#include <hip/hip_runtime.h>
#include <math.h>

#define DM 512
#define NH 8
#define HD 64
#define BB 2
#define TT 2048
#define CHUNK 64
#define NC (TT / CHUNK)   /* 32 */
#define BH (BB * NH)      /* 16 */
#define ROWS (BB * TT)    /* 4096 */
#define EPSV 1e-6f

typedef short bf16x8 __attribute__((ext_vector_type(8)));
typedef float f32x4 __attribute__((ext_vector_type(4)));

__device__ __forceinline__ unsigned short f2bf(float f) {
    unsigned int u = __float_as_uint(f);
    unsigned int r = (u + 0x7FFFu + ((u >> 16) & 1u)) >> 16;
    return (unsigned short)r;
}

__device__ __forceinline__ void gload16(const void* g, void* l) {
    __builtin_amdgcn_global_load_lds(
        (const __attribute__((address_space(1))) unsigned int*)g,
        (__attribute__((address_space(3))) unsigned int*)l, 16, 0, 0);
}

union U4 { unsigned short h[4]; uint2 u; };

// ---------------------------------------------------------------------------
// x (4096x512 f32) -> xb (bf16 bits)
// ---------------------------------------------------------------------------
__global__ __launch_bounds__(256) void cvt_x(
    const float* __restrict__ x, unsigned short* __restrict__ xb)
{
    const int i = blockIdx.x * 256 + threadIdx.x;   // float4 index
    if (i < (ROWS * DM) / 4) {
        float4 v = ((const float4*)x)[i];
        U4 o;
        o.h[0] = f2bf(v.x); o.h[1] = f2bf(v.y);
        o.h[2] = f2bf(v.z); o.h[3] = f2bf(v.w);
        ((uint2*)xb)[i] = o.u;
    }
}

// ---------------------------------------------------------------------------
// W (512x512 f32, row-major [k][n]) -> WT (bf16, [n][k])  for all 4 weights
// ---------------------------------------------------------------------------
__global__ __launch_bounds__(256) void wtrans(
    const float* __restrict__ Wq, const float* __restrict__ Wk,
    const float* __restrict__ Wv, const float* __restrict__ Wo,
    unsigned short* __restrict__ qT, unsigned short* __restrict__ kT,
    unsigned short* __restrict__ vT, unsigned short* __restrict__ oT)
{
    const int which = blockIdx.z;
    const float* W = (which == 0) ? Wq : (which == 1) ? Wk : (which == 2) ? Wv : Wo;
    unsigned short* O = (which == 0) ? qT : (which == 1) ? kT : (which == 2) ? vT : oT;

    __shared__ float t[32][33];
    const int r0 = blockIdx.x * 32, c0 = blockIdx.y * 32;
    const int tr = threadIdx.x >> 3, tc = threadIdx.x & 7;

    float4 v = *(const float4*)&W[(size_t)(r0 + tr) * DM + c0 + tc * 4];
    t[tr][tc * 4 + 0] = v.x; t[tr][tc * 4 + 1] = v.y;
    t[tr][tc * 4 + 2] = v.z; t[tr][tc * 4 + 3] = v.w;
    __syncthreads();

    U4 o;
#pragma unroll
    for (int i = 0; i < 4; ++i) o.h[i] = f2bf(t[tc * 4 + i][tr]);
    *(uint2*)&O[(size_t)(c0 + tr) * DM + r0 + tc * 4] = o.u;
}

// ---------------------------------------------------------------------------
// QKV projection, bf16 MFMA.  C = xb @ W (+bias, +phi), scattered (B,H,T,D).
// 128x128 tile, BK=32, 4 waves (2x2), 16x16x32 MFMA, global_load_lds w=16.
// ---------------------------------------------------------------------------
__global__ __launch_bounds__(256) void qkv_mfma(
    const unsigned short* __restrict__ xb,
    const unsigned short* __restrict__ WqT, const unsigned short* __restrict__ WkT,
    const unsigned short* __restrict__ WvT,
    const float* __restrict__ bq, const float* __restrict__ bk,
    const float* __restrict__ bv,
    float* __restrict__ q, float* __restrict__ k, float* __restrict__ v)
{
    const int which = blockIdx.z;
    const unsigned short* Bg = (which == 0) ? WqT : (which == 1) ? WkT : WvT;
    const float* bias        = (which == 0) ? bq  : (which == 1) ? bk  : bv;
    float* dst               = (which == 0) ? q   : (which == 1) ? k   : v;

    __shared__ alignas(16) unsigned short Asl[128 * 32];
    __shared__ alignas(16) unsigned short Bsl[128 * 32];

    const int tid = threadIdx.x;
    const int lane = tid & 63, wid = tid >> 6;
    const int wr = wid >> 1, wc = wid & 1;
    const int r0 = blockIdx.x * 128, c0 = blockIdx.y * 128;

    f32x4 acc[4][4] = {};

    const int f0 = tid * 8;             // bf16 flat index into the tile
    const int arow = f0 >> 5, acol = f0 & 31;

    for (int k0 = 0; k0 < DM; k0 += 32) {
        __syncthreads();
        gload16(xb + (size_t)(r0 + arow) * DM + k0 + acol, Asl + f0);
        gload16(xb + (size_t)(r0 + arow + 64) * DM + k0 + acol, Asl + f0 + 2048);
        gload16(Bg + (size_t)(c0 + arow) * DM + k0 + acol, Bsl + f0);
        gload16(Bg + (size_t)(c0 + arow + 64) * DM + k0 + acol, Bsl + f0 + 2048);
        __syncthreads();

        const int lrow = lane & 15, lk = (lane >> 4) * 8;
        bf16x8 af[4], bfr[4];
#pragma unroll
        for (int mi = 0; mi < 4; ++mi)
            af[mi] = *(const bf16x8*)&Asl[(wr * 64 + mi * 16 + lrow) * 32 + lk];
#pragma unroll
        for (int ni = 0; ni < 4; ++ni)
            bfr[ni] = *(const bf16x8*)&Bsl[(wc * 64 + ni * 16 + lrow) * 32 + lk];
#pragma unroll
        for (int mi = 0; mi < 4; ++mi)
#pragma unroll
            for (int ni = 0; ni < 4; ++ni)
                acc[mi][ni] = __builtin_amdgcn_mfma_f32_16x16x32_bf16(
                    af[mi], bfr[ni], acc[mi][ni], 0, 0, 0);
    }

    const bool do_phi = (which < 2);
    const int lrow = lane & 15, lr4 = (lane >> 4) * 4;
#pragma unroll
    for (int mi = 0; mi < 4; ++mi) {
#pragma unroll
        for (int ni = 0; ni < 4; ++ni) {
            const int col = c0 + wc * 64 + ni * 16 + lrow;
            const int h = col >> 6, d = col & 63;
            const float bcol = bias[col];
#pragma unroll
            for (int r = 0; r < 4; ++r) {
                const int row = r0 + wr * 64 + mi * 16 + lr4 + r;
                const int b = row >> 11, t = row & (TT - 1);
                float y = acc[mi][ni][r] + bcol;
                if (do_phi) y = (y > 0.f) ? (y + 1.f) : expf(y);
                dst[((size_t)(b * NH + h) * TT + t) * HD + d] = y;
            }
        }
    }
}

// ---------------------------------------------------------------------------
// Output projection, bf16 MFMA: out = attn(bf16) @ Wo + bo  (f32 out).
// ---------------------------------------------------------------------------
__global__ __launch_bounds__(256) void out_mfma(
    const unsigned short* __restrict__ Ag, const unsigned short* __restrict__ BgT,
    const float* __restrict__ bias, float* __restrict__ out)
{
    __shared__ alignas(16) unsigned short Asl[128 * 32];
    __shared__ alignas(16) unsigned short Bsl[128 * 32];

    const int tid = threadIdx.x;
    const int lane = tid & 63, wid = tid >> 6;
    const int wr = wid >> 1, wc = wid & 1;
    const int r0 = blockIdx.x * 128, c0 = blockIdx.y * 128;

    f32x4 acc[4][4] = {};

    const int f0 = tid * 8;
    const int arow = f0 >> 5, acol = f0 & 31;

    for (int k0 = 0; k0 < DM; k0 += 32) {
        __syncthreads();
        gload16(Ag + (size_t)(r0 + arow) * DM + k0 + acol, Asl + f0);
        gload16(Ag + (size_t)(r0 + arow + 64) * DM + k0 + acol, Asl + f0 + 2048);
        gload16(BgT + (size_t)(c0 + arow) * DM + k0 + acol, Bsl + f0);
        gload16(BgT + (size_t)(c0 + arow + 64) * DM + k0 + acol, Bsl + f0 + 2048);
        __syncthreads();

        const int lrow = lane & 15, lk = (lane >> 4) * 8;
        bf16x8 af[4], bfr[4];
#pragma unroll
        for (int mi = 0; mi < 4; ++mi)
            af[mi] = *(const bf16x8*)&Asl[(wr * 64 + mi * 16 + lrow) * 32 + lk];
#pragma unroll
        for (int ni = 0; ni < 4; ++ni)
            bfr[ni] = *(const bf16x8*)&Bsl[(wc * 64 + ni * 16 + lrow) * 32 + lk];
#pragma unroll
        for (int mi = 0; mi < 4; ++mi)
#pragma unroll
            for (int ni = 0; ni < 4; ++ni)
                acc[mi][ni] = __builtin_amdgcn_mfma_f32_16x16x32_bf16(
                    af[mi], bfr[ni], acc[mi][ni], 0, 0, 0);
    }

    const int lrow = lane & 15, lr4 = (lane >> 4) * 4;
#pragma unroll
    for (int mi = 0; mi < 4; ++mi) {
#pragma unroll
        for (int ni = 0; ni < 4; ++ni) {
            const int col = c0 + wc * 64 + ni * 16 + lrow;
            const float bcol = bias[col];
#pragma unroll
            for (int r = 0; r < 4; ++r) {
                const int row = r0 + wr * 64 + mi * 16 + lr4 + r;
                out[(size_t)row * DM + col] = acc[mi][ni][r] + bcol;
            }
        }
    }
}

// ---------------------------------------------------------------------------
// Kernel: per-chunk sums (fp32).
// ---------------------------------------------------------------------------
__global__ __launch_bounds__(256) void chunk_sums(
    const float* __restrict__ k, const float* __restrict__ v,
    float* __restrict__ kvsum, float* __restrict__ zsum)
{
    const int blk = blockIdx.x;
    const int bh = blk / NC, c = blk % NC;
    const int t0 = c * CHUNK;

    __shared__ float Ks[CHUNK][HD];
    __shared__ float Vs[CHUNK][HD];

    const int tid = threadIdx.x;
    const float* kb = k + ((size_t)bh * TT + t0) * HD;
    const float* vb = v + ((size_t)bh * TT + t0) * HD;

#pragma unroll
    for (int i = 0; i < 4; ++i) {
        const int f = tid + i * 256;
        const int row = f >> 4, col = (f & 15) * 4;
        *(float4*)&Ks[row][col] = *(const float4*)&kb[row * HD + col];
        *(float4*)&Vs[row][col] = *(const float4*)&vb[row * HD + col];
    }
    __syncthreads();

    const int ti = tid >> 4, tj = tid & 15;
    float acc[4][4] = {};
    for (int t = 0; t < CHUNK; ++t) {
        float4 k4 = *(const float4*)&Ks[t][ti * 4];
        float4 v4 = *(const float4*)&Vs[t][tj * 4];
        float km[4] = {k4.x, k4.y, k4.z, k4.w};
        float vm[4] = {v4.x, v4.y, v4.z, v4.w};
#pragma unroll
        for (int i = 0; i < 4; ++i)
#pragma unroll
            for (int j = 0; j < 4; ++j)
                acc[i][j] = fmaf(km[i], vm[j], acc[i][j]);
    }

    float* dst = kvsum + (size_t)blk * (HD * HD);
#pragma unroll
    for (int i = 0; i < 4; ++i)
#pragma unroll
        for (int j = 0; j < 4; ++j)
            dst[(ti * 4 + i) * HD + tj * 4 + j] = acc[i][j];

    if (tid < HD) {
        float s = 0.f;
        for (int t = 0; t < CHUNK; ++t) s += Ks[t][tid];
        zsum[(size_t)blk * HD + tid] = s;
    }
}

// ---------------------------------------------------------------------------
// Kernel: exclusive prefix over chunks.
// ---------------------------------------------------------------------------
__global__ __launch_bounds__(256) void prefix_scan(
    float* __restrict__ kvsum, float* __restrict__ zsum)
{
    const int bh = blockIdx.x;
    const int seg = blockIdx.y;
    const int tid = threadIdx.x;

    if (seg < 16) {
        const int e = seg * 256 + tid;
        float run = 0.f;
        for (int c = 0; c < NC; ++c) {
            const size_t idx = (size_t)(bh * NC + c) * (HD * HD) + e;
            const float val = kvsum[idx];
            kvsum[idx] = run;
            run += val;
        }
    } else if (tid < HD) {
        float run = 0.f;
        for (int c = 0; c < NC; ++c) {
            const size_t idx = (size_t)(bh * NC + c) * HD + tid;
            const float val = zsum[idx];
            zsum[idx] = run;
            run += val;
        }
    }
}

// ---------------------------------------------------------------------------
// Kernel: per-chunk attention (fp32 math), writes bf16 attn (B,T,DM).
// ---------------------------------------------------------------------------
__global__ __launch_bounds__(256) void chunk_attn(
    const float* __restrict__ q, const float* __restrict__ k,
    const float* __restrict__ v, const float* __restrict__ sprev,
    const float* __restrict__ zprev_g, unsigned short* __restrict__ attn)
{
    const int blk = blockIdx.x;
    const int bh = blk / NC, c = blk % NC;
    const int t0 = c * CHUNK;

    __shared__ float Qs[CHUNK][HD + 1];
    __shared__ float KA[CHUNK][HD + 1];
    __shared__ float Vs[CHUNK][HD];
    __shared__ float Ss[HD][HD];
    __shared__ float zprev[HD];
    __shared__ float den[CHUNK];

    const int tid = threadIdx.x;
    const float* qb = q + ((size_t)bh * TT + t0) * HD;
    const float* kb = k + ((size_t)bh * TT + t0) * HD;
    const float* vb = v + ((size_t)bh * TT + t0) * HD;
    const float* sb = sprev + (size_t)blk * (HD * HD);

#pragma unroll
    for (int i = 0; i < 4; ++i) {
        const int f = tid + i * 256;
        const int row = f >> 4, col = (f & 15) * 4;
        float4 q4 = *(const float4*)&qb[row * HD + col];
        float4 k4 = *(const float4*)&kb[row * HD + col];
        Qs[row][col + 0] = q4.x; Qs[row][col + 1] = q4.y;
        Qs[row][col + 2] = q4.z; Qs[row][col + 3] = q4.w;
        KA[row][col + 0] = k4.x; KA[row][col + 1] = k4.y;
        KA[row][col + 2] = k4.z; KA[row][col + 3] = k4.w;
        *(float4*)&Vs[row][col] = *(const float4*)&vb[row * HD + col];
        *(float4*)&Ss[row][col] = *(const float4*)&sb[row * HD + col];
    }
    if (tid < HD) zprev[tid] = zprev_g[(size_t)blk * HD + tid];
    __syncthreads();

    const int ti = tid >> 4, tj = tid & 15;

    float sc[4][4] = {};
#pragma unroll 8
    for (int d = 0; d < HD; ++d) {
        float qv[4], kv4[4];
#pragma unroll
        for (int i = 0; i < 4; ++i) qv[i] = Qs[ti * 4 + i][d];
#pragma unroll
        for (int j = 0; j < 4; ++j) kv4[j] = KA[tj * 4 + j][d];
#pragma unroll
        for (int i = 0; i < 4; ++i)
#pragma unroll
            for (int j = 0; j < 4; ++j)
                sc[i][j] = fmaf(qv[i], kv4[j], sc[i][j]);
    }
    __syncthreads();

#pragma unroll
    for (int i = 0; i < 4; ++i)
#pragma unroll
        for (int j = 0; j < 4; ++j) {
            const int row = ti * 4 + i, col = tj * 4 + j;
            KA[row][col] = (col <= row) ? sc[i][j] : 0.f;
        }
    __syncthreads();

    if (tid < CHUNK) {
        float dsum = 0.f;
        for (int d = 0; d < HD; ++d) dsum = fmaf(Qs[tid][d], zprev[d], dsum);
        for (int j = 0; j < HD; ++j) dsum += KA[tid][j];
        den[tid] = fmaxf(dsum, EPSV);
    }
    __syncthreads();

    float accn[4][4] = {};
#pragma unroll 4
    for (int jj = 0; jj < CHUNK; ++jj) {
        const float4 v4 = *(const float4*)&Vs[jj][tj * 4];
        float am[4];
#pragma unroll
        for (int i = 0; i < 4; ++i) am[i] = KA[ti * 4 + i][jj];
        const float vm[4] = {v4.x, v4.y, v4.z, v4.w};
#pragma unroll
        for (int i = 0; i < 4; ++i)
#pragma unroll
            for (int j = 0; j < 4; ++j)
                accn[i][j] = fmaf(am[i], vm[j], accn[i][j]);
    }
#pragma unroll 4
    for (int d = 0; d < HD; ++d) {
        const float4 s4 = *(const float4*)&Ss[d][tj * 4];
        float qv[4];
#pragma unroll
        for (int i = 0; i < 4; ++i) qv[i] = Qs[ti * 4 + i][d];
        const float sm[4] = {s4.x, s4.y, s4.z, s4.w};
#pragma unroll
        for (int i = 0; i < 4; ++i)
#pragma unroll
            for (int j = 0; j < 4; ++j)
                accn[i][j] = fmaf(qv[i], sm[j], accn[i][j]);
    }

    const int b = bh >> 3, h = bh & 7;
#pragma unroll
    for (int i = 0; i < 4; ++i) {
        const int trow = t0 + ti * 4 + i;
        const float dv = den[ti * 4 + i];
        unsigned short* dstp = attn + ((size_t)b * TT + trow) * DM + h * HD + tj * 4;
        U4 o;
#pragma unroll
        for (int j = 0; j < 4; ++j) o.h[j] = f2bf(accn[i][j] / dv);
        *(uint2*)dstp = o.u;
    }
}

// ---------------------------------------------------------------------------
extern "C" void kernel_launch(void* const* d_in, const int* in_sizes, int n_in,
                              void* d_out, int out_size, void* d_ws, size_t ws_size,
                              hipStream_t stream)
{
    const float* x  = (const float*)d_in[0];
    const float* Wq = (const float*)d_in[1];
    const float* bq = (const float*)d_in[2];
    const float* Wk = (const float*)d_in[3];
    const float* bk = (const float*)d_in[4];
    const float* Wv = (const float*)d_in[5];
    const float* bv = (const float*)d_in[6];
    const float* Wo = (const float*)d_in[7];
    const float* bo = (const float*)d_in[8];
    float* out = (float*)d_out;

    const size_t SZ = (size_t)BH * TT * HD;            // 2,097,152
    unsigned short* xb  = (unsigned short*)d_ws;       // 4 MB
    unsigned short* WqT = xb + SZ;                     // 512 KB each
    unsigned short* WkT = WqT + DM * DM;
    unsigned short* WvT = WkT + DM * DM;
    unsigned short* WoT = WvT + DM * DM;
    float* q     = (float*)(WoT + DM * DM);            // 8 MB each
    float* k     = q + SZ;
    float* v     = k + SZ;
    float* kvsum = v + SZ;                             // 8 MB
    float* zsum  = kvsum + (size_t)BH * NC * HD * HD;  // 128 KB
    unsigned short* attn = xb;                         // alias: xb dead after qkv_mfma

    cvt_x<<<(ROWS * DM / 4 + 255) / 256, 256, 0, stream>>>(x, xb);
    wtrans<<<dim3(16, 16, 4), 256, 0, stream>>>(Wq, Wk, Wv, Wo, WqT, WkT, WvT, WoT);
    qkv_mfma<<<dim3(ROWS / 128, DM / 128, 3), 256, 0, stream>>>(
        xb, WqT, WkT, WvT, bq, bk, bv, q, k, v);
    chunk_sums<<<BH * NC, 256, 0, stream>>>(k, v, kvsum, zsum);
    prefix_scan<<<dim3(BH, 17), 256, 0, stream>>>(kvsum, zsum);
    chunk_attn<<<BH * NC, 256, 0, stream>>>(q, k, v, kvsum, zsum, attn);
    out_mfma<<<dim3(ROWS / 128, DM / 128), 256, 0, stream>>>(attn, WoT, bo, out);
}

// Round 3
// 48.393 us; speedup vs baseline: 3.3391x; 1.5999x over previous
//
#include <hip/hip_runtime.h>
#include <math.h>

#define DM 512
#define NH 8
#define HD 64
#define BB 2
#define TT 2048
#define CHUNK 64
#define NC (TT / CHUNK)   /* 32 */
#define BH (BB * NH)      /* 16 */
#define ROWS (BB * TT)    /* 4096 */
#define EPSV 1e-6f

typedef short bf16x8 __attribute__((ext_vector_type(8)));
typedef float f32x4 __attribute__((ext_vector_type(4)));
typedef unsigned short us;

union U4 { us h[4]; uint2 u; };

__device__ __forceinline__ us f2bf(float f) {
    unsigned int u = __float_as_uint(f);
    return (us)((u + 0x7FFFu + ((u >> 16) & 1u)) >> 16);
}
__device__ __forceinline__ float bf2f(us h) {
    return __uint_as_float(((unsigned int)h) << 16);
}
__device__ __forceinline__ void gload16(const void* g, void* l) {
    __builtin_amdgcn_global_load_lds(
        (const __attribute__((address_space(1))) unsigned int*)g,
        (__attribute__((address_space(3))) unsigned int*)l, 16, 0, 0);
}
// XOR swizzle: permutes 16B blocks (elem bits 3..5) within a 64-elem row by
// row&7 -> frag ds_read_b128 across 16 rows hits 32 banks at 2 lanes/bank.
#define SWZ(r, k) ((k) ^ (((r) & 7) << 3))

// ---------------------------------------------------------------------------
// prep: blocks [0,2048): x f32 -> xb bf16.  blocks [2048,3072): W -> W^T bf16.
// ---------------------------------------------------------------------------
__global__ __launch_bounds__(256) void prep(
    const float* __restrict__ x,
    const float* __restrict__ Wq, const float* __restrict__ Wk,
    const float* __restrict__ Wv, const float* __restrict__ Wo,
    us* __restrict__ xb, us* __restrict__ WT)
{
    const int bid = blockIdx.x, tid = threadIdx.x;
    __shared__ float tl[32][33];
    if (bid < 2048) {
        const int i = bid * 256 + tid;
        float4 v = ((const float4*)x)[i];
        U4 o;
        o.h[0] = f2bf(v.x); o.h[1] = f2bf(v.y);
        o.h[2] = f2bf(v.z); o.h[3] = f2bf(v.w);
        ((uint2*)xb)[i] = o.u;
    } else {
        const int b2 = bid - 2048;
        const int which = b2 >> 8, t = b2 & 255;
        const float* W = (which == 0) ? Wq : (which == 1) ? Wk : (which == 2) ? Wv : Wo;
        us* O = WT + (size_t)which * DM * DM;
        const int r0 = (t >> 4) * 32, c0 = (t & 15) * 32;
        const int tr = tid >> 3, tc = tid & 7;
        float4 v = *(const float4*)&W[(size_t)(r0 + tr) * DM + c0 + tc * 4];
        tl[tr][tc * 4 + 0] = v.x; tl[tr][tc * 4 + 1] = v.y;
        tl[tr][tc * 4 + 2] = v.z; tl[tr][tc * 4 + 3] = v.w;
        __syncthreads();
        U4 o;
#pragma unroll
        for (int i = 0; i < 4; ++i) o.h[i] = f2bf(tl[tc * 4 + i][tr]);
        *(uint2*)&O[(size_t)(c0 + tr) * DM + r0 + tc * 4] = o.u;
    }
}

// ---------------------------------------------------------------------------
// Shared 64x128 GEMM core: C[64x128] = A[64xDM] @ Bstore[128xDM]^T (bf16).
// BK=64, swizzled LDS, 4 waves (2x2), wave-tile 32x64.
// ---------------------------------------------------------------------------
__device__ __forceinline__ void gemm64x128(
    const us* __restrict__ Ag, const us* __restrict__ Bg,
    int r0, int c0, int tid, us* Asl, us* Bsl, f32x4 (&acc)[2][4])
{
    const int lane = tid & 63, wid = tid >> 6;
    const int wr = wid >> 1, wc = wid & 1;
    const int lrow = lane & 15, lk8 = (lane >> 4) * 8;
    const int fa = tid * 8;

    for (int k0 = 0; k0 < DM; k0 += 64) {
        __syncthreads();
#pragma unroll
        for (int i = 0; i < 2; ++i) {
            const int f = fa + i * 2048, row = f >> 6, kp = f & 63;
            gload16(Ag + (size_t)(r0 + row) * DM + k0 + SWZ(row, kp), Asl + f);
        }
#pragma unroll
        for (int i = 0; i < 4; ++i) {
            const int f = fa + i * 2048, row = f >> 6, kp = f & 63;
            gload16(Bg + (size_t)(c0 + row) * DM + k0 + SWZ(row, kp), Bsl + f);
        }
        __syncthreads();
#pragma unroll
        for (int kin = 0; kin < 64; kin += 32) {
            bf16x8 af[2], bfr[4];
#pragma unroll
            for (int mi = 0; mi < 2; ++mi) {
                const int row = wr * 32 + mi * 16 + lrow;
                af[mi] = *(const bf16x8*)&Asl[row * 64 + SWZ(row, kin + lk8)];
            }
#pragma unroll
            for (int ni = 0; ni < 4; ++ni) {
                const int row = wc * 64 + ni * 16 + lrow;
                bfr[ni] = *(const bf16x8*)&Bsl[row * 64 + SWZ(row, kin + lk8)];
            }
#pragma unroll
            for (int mi = 0; mi < 2; ++mi)
#pragma unroll
                for (int ni = 0; ni < 4; ++ni)
                    acc[mi][ni] = __builtin_amdgcn_mfma_f32_16x16x32_bf16(
                        af[mi], bfr[ni], acc[mi][ni], 0, 0, 0);
        }
    }
}

// ---------------------------------------------------------------------------
// QKV projection: bf16 out.  Q natural [bh][t][d]; K natural AND transposed
// [bh][d][t]; V transposed only.  phi on Q,K.
// ---------------------------------------------------------------------------
__global__ __launch_bounds__(256) void qkv_mfma(
    const us* __restrict__ xb, const us* __restrict__ WT,
    const float* __restrict__ bq, const float* __restrict__ bk,
    const float* __restrict__ bv,
    us* __restrict__ qn, us* __restrict__ kn,
    us* __restrict__ kt, us* __restrict__ vt)
{
    const int which = blockIdx.z;
    const us* Bg = WT + (size_t)which * DM * DM;
    const float* bias = (which == 0) ? bq : (which == 1) ? bk : bv;

    __shared__ us Asl[64 * 64];
    __shared__ us Bsl[128 * 64];
    f32x4 acc[2][4] = {};
    const int r0 = blockIdx.x * 64, c0 = blockIdx.y * 128;
    const int tid = threadIdx.x;

    gemm64x128(xb, Bg, r0, c0, tid, Asl, Bsl, acc);

    const int lane = tid & 63, wid = tid >> 6;
    const int wr = wid >> 1, wc = wid & 1;
    const int lrow = lane & 15, lr4 = (lane >> 4) * 4;
    const int b = r0 >> 11;                       // batch (r0 mult of 64)

#pragma unroll
    for (int mi = 0; mi < 2; ++mi) {
        const int rowb = r0 + wr * 32 + mi * 16 + lr4;
        const int t0g = rowb & (TT - 1);
#pragma unroll
        for (int ni = 0; ni < 4; ++ni) {
            const int col = c0 + wc * 64 + ni * 16 + lrow;
            const int h = col >> 6, d = col & 63;
            const float bc = bias[col];
            U4 p4;
#pragma unroll
            for (int r = 0; r < 4; ++r) {
                float y = acc[mi][ni][r] + bc;
                if (which < 2) y = (y > 0.f) ? (y + 1.f) : __expf(y);
                const us hb = f2bf(y);
                p4.h[r] = hb;
                if (which == 0)
                    qn[((size_t)(b * NH + h) * TT + t0g + r) * HD + d] = hb;
                else if (which == 1)
                    kn[((size_t)(b * NH + h) * TT + t0g + r) * HD + d] = hb;
            }
            if (which == 1)
                *(uint2*)&kt[((size_t)(b * NH + h) * HD + d) * TT + t0g] = p4.u;
            else if (which == 2)
                *(uint2*)&vt[((size_t)(b * NH + h) * HD + d) * TT + t0g] = p4.u;
        }
    }
}

// ---------------------------------------------------------------------------
// Output projection: out = attn(bf16) @ Wo^T + bo, f32 out.
// ---------------------------------------------------------------------------
__global__ __launch_bounds__(256) void out_mfma(
    const us* __restrict__ Ag, const us* __restrict__ WoT,
    const float* __restrict__ bias, float* __restrict__ out)
{
    __shared__ us Asl[64 * 64];
    __shared__ us Bsl[128 * 64];
    f32x4 acc[2][4] = {};
    const int r0 = blockIdx.x * 64, c0 = blockIdx.y * 128;
    const int tid = threadIdx.x;

    gemm64x128(Ag, WoT, r0, c0, tid, Asl, Bsl, acc);

    const int lane = tid & 63, wid = tid >> 6;
    const int wr = wid >> 1, wc = wid & 1;
    const int lrow = lane & 15, lr4 = (lane >> 4) * 4;

#pragma unroll
    for (int mi = 0; mi < 2; ++mi)
#pragma unroll
        for (int ni = 0; ni < 4; ++ni) {
            const int col = c0 + wc * 64 + ni * 16 + lrow;
            const float bc = bias[col];
#pragma unroll
            for (int r = 0; r < 4; ++r) {
                const int row = r0 + wr * 32 + mi * 16 + lr4 + r;
                out[(size_t)row * DM + col] = acc[mi][ni][r] + bc;
            }
        }
}

// ---------------------------------------------------------------------------
// chunk_sums: per (bh,c): S^T_c[d2][d1] = sum_t V[t][d2] K[t][d1] (bf16 out,
// via MFMA over k=t) and z_c[d] = sum_t K[t][d] (f32).
// ---------------------------------------------------------------------------
__global__ __launch_bounds__(256) void chunk_sums(
    const us* __restrict__ kt, const us* __restrict__ vt,
    us* __restrict__ kvc, float* __restrict__ zc)
{
    const int blk = blockIdx.x, bh = blk >> 5, c = blk & 31;
    const int t0 = c * CHUNK;
    __shared__ us Ksl[4096], Vsl[4096];
    __shared__ float partial[4][64];
    const int tid = threadIdx.x;
    const us* ktb = kt + (size_t)bh * HD * TT;
    const us* vtb = vt + (size_t)bh * HD * TT;

#pragma unroll
    for (int i = 0; i < 2; ++i) {
        const int f = tid * 8 + i * 2048, row = f >> 6, kp = f & 63;
        const int kl = SWZ(row, kp);
        gload16(ktb + (size_t)row * TT + t0 + kl, Ksl + f);
        gload16(vtb + (size_t)row * TT + t0 + kl, Vsl + f);
    }
    __syncthreads();

    const int lane = tid & 63, wid = tid >> 6;
    const int wr = wid >> 1, wc = wid & 1;
    const int lrow = lane & 15, lk8 = (lane >> 4) * 8, lr4 = (lane >> 4) * 4;

    f32x4 acc[2][2] = {};
#pragma unroll
    for (int kin = 0; kin < 64; kin += 32) {
        bf16x8 af[2], bfr[2];
#pragma unroll
        for (int mi = 0; mi < 2; ++mi) {
            const int row = wr * 32 + mi * 16 + lrow;
            af[mi] = *(const bf16x8*)&Vsl[row * 64 + SWZ(row, kin + lk8)];
        }
#pragma unroll
        for (int ni = 0; ni < 2; ++ni) {
            const int row = wc * 32 + ni * 16 + lrow;
            bfr[ni] = *(const bf16x8*)&Ksl[row * 64 + SWZ(row, kin + lk8)];
        }
#pragma unroll
        for (int mi = 0; mi < 2; ++mi)
#pragma unroll
            for (int ni = 0; ni < 2; ++ni)
                acc[mi][ni] = __builtin_amdgcn_mfma_f32_16x16x32_bf16(
                    af[mi], bfr[ni], acc[mi][ni], 0, 0, 0);
    }

    us* dst = kvc + (size_t)blk * 4096;
#pragma unroll
    for (int mi = 0; mi < 2; ++mi)
#pragma unroll
        for (int ni = 0; ni < 2; ++ni) {
            const int d2 = wr * 32 + mi * 16 + lr4;
            const int d1 = wc * 32 + ni * 16 + lrow;
#pragma unroll
            for (int r = 0; r < 4; ++r)
                dst[(d2 + r) * 64 + d1] = f2bf(acc[mi][ni][r]);
        }

    // z: row sums of K^T (logical [d][t])
    {
        const int p = tid >> 6, d = tid & 63;
        float s = 0.f;
#pragma unroll
        for (int j = 0; j < 16; ++j)
            s += bf2f(Ksl[d * 64 + SWZ(d, p * 16 + j)]);
        partial[p][d] = s;
    }
    __syncthreads();
    if (tid < 64)
        zc[(size_t)blk * 64 + tid] =
            partial[0][tid] + partial[1][tid] + partial[2][tid] + partial[3][tid];
}

// ---------------------------------------------------------------------------
// scan: exclusive prefix over chunks.  kvc bf16 -> spr bf16 (f32 running sum
// in registers); zc f32 -> zpr f32.
// ---------------------------------------------------------------------------
__global__ __launch_bounds__(256) void scan(
    const us* __restrict__ kvc, const float* __restrict__ zc,
    us* __restrict__ spr, float* __restrict__ zpr)
{
    const int bh = blockIdx.x, seg = blockIdx.y, tid = threadIdx.x;
    if (seg < 8) {
        const int e = seg * 512 + tid * 2;
        float r0 = 0.f, r1 = 0.f;
        for (int c = 0; c < NC; ++c) {
            const size_t off = (size_t)(bh * NC + c) * 4096 + e;
            const unsigned u = *(const unsigned*)(kvc + off);
            const unsigned p = (unsigned)f2bf(r0) | ((unsigned)f2bf(r1) << 16);
            *(unsigned*)(spr + off) = p;
            r0 += bf2f((us)(u & 0xFFFF));
            r1 += bf2f((us)(u >> 16));
        }
    } else if (tid < 64) {
        float run = 0.f;
        for (int c = 0; c < NC; ++c) {
            const size_t off = (size_t)(bh * NC + c) * 64 + tid;
            zpr[off] = run;
            run += zc[off];
        }
    }
}

// ---------------------------------------------------------------------------
// chunk_attn: MFMA QK^T -> mask -> den -> MFMA (A@V + Q@S) -> /den -> bf16.
// ---------------------------------------------------------------------------
__global__ __launch_bounds__(256) void chunk_attn(
    const us* __restrict__ qn, const us* __restrict__ kn,
    const us* __restrict__ vt, const us* __restrict__ spr,
    const float* __restrict__ zpr, us* __restrict__ attn)
{
    const int blk = blockIdx.x, bh = blk >> 5, c = blk & 31;
    const int t0 = c * CHUNK;
    __shared__ us Qs[4096], Kns[4096], Vts[4096], Sts[4096], Abf[4096];
    __shared__ float zp[64], den[64], part[4][64];
    const int tid = threadIdx.x;

    const us* qb = qn + ((size_t)bh * TT + t0) * HD;
    const us* kb = kn + ((size_t)bh * TT + t0) * HD;
    const us* vb = vt + (size_t)bh * HD * TT;
    const us* sb = spr + (size_t)blk * 4096;

#pragma unroll
    for (int i = 0; i < 2; ++i) {
        const int f = tid * 8 + i * 2048, row = f >> 6, kp = f & 63;
        const int kl = SWZ(row, kp);
        gload16(qb + (size_t)row * HD + kl, Qs + f);
        gload16(kb + (size_t)row * HD + kl, Kns + f);
        gload16(vb + (size_t)row * TT + t0 + kl, Vts + f);
        gload16(sb + (size_t)row * 64 + kl, Sts + f);
    }
    if (tid < 64) zp[tid] = zpr[(size_t)blk * 64 + tid];
    __syncthreads();

    const int lane = tid & 63, wid = tid >> 6;
    const int wr = wid >> 1, wc = wid & 1;
    const int lrow = lane & 15, lk8 = (lane >> 4) * 8, lr4 = (lane >> 4) * 4;

    // QK^T
    f32x4 accs[2][2] = {};
#pragma unroll
    for (int kin = 0; kin < 64; kin += 32) {
        bf16x8 af[2], bfr[2];
#pragma unroll
        for (int mi = 0; mi < 2; ++mi) {
            const int row = wr * 32 + mi * 16 + lrow;
            af[mi] = *(const bf16x8*)&Qs[row * 64 + SWZ(row, kin + lk8)];
        }
#pragma unroll
        for (int ni = 0; ni < 2; ++ni) {
            const int row = wc * 32 + ni * 16 + lrow;
            bfr[ni] = *(const bf16x8*)&Kns[row * 64 + SWZ(row, kin + lk8)];
        }
#pragma unroll
        for (int mi = 0; mi < 2; ++mi)
#pragma unroll
            for (int ni = 0; ni < 2; ++ni)
                accs[mi][ni] = __builtin_amdgcn_mfma_f32_16x16x32_bf16(
                    af[mi], bfr[ni], accs[mi][ni], 0, 0, 0);
    }

    // mask + bf16 store of scores
#pragma unroll
    for (int mi = 0; mi < 2; ++mi)
#pragma unroll
        for (int ni = 0; ni < 2; ++ni) {
            const int j = wc * 32 + ni * 16 + lrow;
#pragma unroll
            for (int r = 0; r < 4; ++r) {
                const int i = wr * 32 + mi * 16 + lr4 + r;
                const float v = (j <= i) ? accs[mi][ni][r] : 0.f;
                Abf[i * 64 + SWZ(i, j)] = f2bf(v);
            }
        }
    __syncthreads();

    // den[i] = rowsum(A[i][:]) + Q[i].z_prev   (4-way split + combine)
    {
        const int p = tid >> 6, i = tid & 63;
        float s = 0.f;
#pragma unroll
        for (int jj = 0; jj < 16; ++jj) {
            const int j = p * 16 + jj;
            s += bf2f(Abf[i * 64 + SWZ(i, j)]);
            s += bf2f(Qs[i * 64 + SWZ(i, j)]) * zp[j];
        }
        part[p][i] = s;
    }
    __syncthreads();
    if (tid < 64)
        den[tid] = fmaxf(part[0][tid] + part[1][tid] + part[2][tid] + part[3][tid], EPSV);
    __syncthreads();

    // num = A @ V + Q @ S_prev
    f32x4 acco[2][2] = {};
#pragma unroll
    for (int kin = 0; kin < 64; kin += 32) {
        bf16x8 af[2], bfr[2], ag[2], bgr[2];
#pragma unroll
        for (int mi = 0; mi < 2; ++mi) {
            const int row = wr * 32 + mi * 16 + lrow;
            af[mi] = *(const bf16x8*)&Abf[row * 64 + SWZ(row, kin + lk8)];
            ag[mi] = *(const bf16x8*)&Qs[row * 64 + SWZ(row, kin + lk8)];
        }
#pragma unroll
        for (int ni = 0; ni < 2; ++ni) {
            const int row = wc * 32 + ni * 16 + lrow;
            bfr[ni] = *(const bf16x8*)&Vts[row * 64 + SWZ(row, kin + lk8)];
            bgr[ni] = *(const bf16x8*)&Sts[row * 64 + SWZ(row, kin + lk8)];
        }
#pragma unroll
        for (int mi = 0; mi < 2; ++mi)
#pragma unroll
            for (int ni = 0; ni < 2; ++ni) {
                acco[mi][ni] = __builtin_amdgcn_mfma_f32_16x16x32_bf16(
                    af[mi], bfr[ni], acco[mi][ni], 0, 0, 0);
                acco[mi][ni] = __builtin_amdgcn_mfma_f32_16x16x32_bf16(
                    ag[mi], bgr[ni], acco[mi][ni], 0, 0, 0);
            }
    }

    const int b = bh >> 3, h = bh & 7;
#pragma unroll
    for (int mi = 0; mi < 2; ++mi)
#pragma unroll
        for (int ni = 0; ni < 2; ++ni) {
            const int d2 = wc * 32 + ni * 16 + lrow;
#pragma unroll
            for (int r = 0; r < 4; ++r) {
                const int i = wr * 32 + mi * 16 + lr4 + r;
                attn[((size_t)b * TT + t0 + i) * DM + h * HD + d2] =
                    f2bf(acco[mi][ni][r] / den[i]);
            }
        }
}

// ---------------------------------------------------------------------------
extern "C" void kernel_launch(void* const* d_in, const int* in_sizes, int n_in,
                              void* d_out, int out_size, void* d_ws, size_t ws_size,
                              hipStream_t stream)
{
    const float* x  = (const float*)d_in[0];
    const float* Wq = (const float*)d_in[1];
    const float* bq = (const float*)d_in[2];
    const float* Wk = (const float*)d_in[3];
    const float* bk = (const float*)d_in[4];
    const float* Wv = (const float*)d_in[5];
    const float* bv = (const float*)d_in[6];
    const float* Wo = (const float*)d_in[7];
    const float* bo = (const float*)d_in[8];
    float* out = (float*)d_out;

    const size_t SZ = (size_t)BH * TT * HD;        // 2,097,152 elems
    us* xb  = (us*)d_ws;                            // also aliased as attn
    us* WT  = xb + SZ;                              // 4 transposed weights
    us* qn  = WT + (size_t)4 * DM * DM;
    us* kn  = qn + SZ;
    us* kt  = kn + SZ;
    us* vt  = kt + SZ;
    us* kvc = vt + SZ;                              // BH*NC*4096 = SZ
    us* spr = kvc + SZ;
    float* zc  = (float*)(spr + SZ);                // BH*NC*64 f32
    float* zpr = zc + (size_t)BH * NC * 64;
    us* attn = xb;                                  // xb dead after qkv_mfma

    prep<<<3072, 256, 0, stream>>>(x, Wq, Wk, Wv, Wo, xb, WT);
    qkv_mfma<<<dim3(ROWS / 64, DM / 128, 3), 256, 0, stream>>>(
        xb, WT, bq, bk, bv, qn, kn, kt, vt);
    chunk_sums<<<BH * NC, 256, 0, stream>>>(kt, vt, kvc, zc);
    scan<<<dim3(BH, 9), 256, 0, stream>>>(kvc, zc, spr, zpr);
    chunk_attn<<<BH * NC, 256, 0, stream>>>(qn, kn, vt, spr, zpr, attn);
    out_mfma<<<dim3(ROWS / 64, DM / 128), 256, 0, stream>>>(attn, WT + (size_t)3 * DM * DM, bo, out);
}